// Round 2
// baseline (1973.580 us; speedup 1.0000x reference)
//
#include <hip/hip_runtime.h>

typedef unsigned int u32;
typedef unsigned long long u64;
typedef unsigned short u16;

#define DEVFN static __device__ __forceinline__

constexpr int NPTS = 16384;  // points per batch
constexpr int NC = 512;      // centers per batch
// B=8, K=32, FEAT=256

typedef __attribute__((ext_vector_type(8))) short bf16x8;
typedef __attribute__((ext_vector_type(4))) float f32x4;

#define MFMA16(a, b, c) __builtin_amdgcn_mfma_f32_16x16x32_bf16(a, b, c, 0, 0, 0)

DEVFN u16 bf16rne(float f) {
  u32 b = __float_as_uint(f);
  u32 r = (b + 0x7FFFu + ((b >> 16) & 1u)) >> 16;
  return (u16)r;
}

DEVFN u64 shflx64(u64 v, int m) {
  u32 lo = __shfl_xor((u32)v, m, 64);
  u32 hi = __shfl_xor((u32)(v >> 32), m, 64);
  return ((u64)hi << 32) | lo;
}
DEVFN u64 shfl64(u64 v, int src) {
  u32 lo = __shfl((u32)v, src, 64);
  u32 hi = __shfl((u32)(v >> 32), src, 64);
  return ((u64)hi << 32) | lo;
}

DEVFN void csw(u64& a, u64& b) {
  u64 lo = a < b ? a : b;
  u64 hi = a < b ? b : a;
  a = lo; b = hi;
}

// ---------------------------------------------------------------------------
// FPS: one block per batch. Exact numpy-matching arithmetic (no FMA, same
// association), argmax tie-break = lowest index via packed (bits<<32)|~idx.
// ---------------------------------------------------------------------------
__global__ __launch_bounds__(1024) void fps_kernel(const float* __restrict__ xyz,
                                                   float* __restrict__ centers) {
  const int b = blockIdx.x;
  const int t = threadIdx.x;
  const float* xb = xyz + (size_t)b * NPTS * 3;
  float px[16], py[16], pz[16], md[16];
  u32 nidx[16];
#pragma unroll
  for (int j = 0; j < 16; ++j) {
    int p = t + j * 1024;
    px[j] = xb[p * 3 + 0];
    py[j] = xb[p * 3 + 1];
    pz[j] = xb[p * 3 + 2];
    md[j] = 1e10f;
    nidx[j] = ~(u32)p;
  }
  __shared__ u64 skey[16];
  __shared__ float sc[3];
  float cx = xb[0], cy = xb[1], cz = xb[2];
  if (t == 0) {
    centers[(b * NC) * 3 + 0] = cx;
    centers[(b * NC) * 3 + 1] = cy;
    centers[(b * NC) * 3 + 2] = cz;
  }
  const int lane = t & 63;
  const int wv = t >> 6;
  for (int i = 1; i < NC; ++i) {
    u64 best = 0;
#pragma unroll
    for (int j = 0; j < 16; ++j) {
      float dx = __fsub_rn(px[j], cx);
      float dy = __fsub_rn(py[j], cy);
      float dz = __fsub_rn(pz[j], cz);
      float d = __fadd_rn(__fadd_rn(__fmul_rn(dx, dx), __fmul_rn(dy, dy)), __fmul_rn(dz, dz));
      md[j] = fminf(md[j], d);
      u64 key = ((u64)__float_as_uint(md[j]) << 32) | (u64)nidx[j];
      best = key > best ? key : best;
    }
#pragma unroll
    for (int s = 32; s; s >>= 1) {
      u64 o = shflx64(best, s);
      best = o > best ? o : best;
    }
    if (lane == 0) skey[wv] = best;
    __syncthreads();
    u64 g = skey[0];
#pragma unroll
    for (int q = 1; q < 16; ++q) {
      u64 o = skey[q];
      g = o > g ? o : g;
    }
    u32 widx = ~(u32)g;  // winner original index
    if ((widx & 1023u) == (u32)t) {
      int jw = (int)(widx >> 10);
      float bx = 0.f, by = 0.f, bz = 0.f;
#pragma unroll
      for (int j = 0; j < 16; ++j)
        if (j == jw) { bx = px[j]; by = py[j]; bz = pz[j]; }
      sc[0] = bx; sc[1] = by; sc[2] = bz;
      centers[(b * NC + i) * 3 + 0] = bx;
      centers[(b * NC + i) * 3 + 1] = by;
      centers[(b * NC + i) * 3 + 2] = bz;
    }
    __syncthreads();
    cx = sc[0]; cy = sc[1]; cz = sc[2];
  }
}

// ---------------------------------------------------------------------------
// KNN: 8 waves/block, wave = one center. Exact top-32 set by (d, idx).
// ---------------------------------------------------------------------------
__global__ __launch_bounds__(512) void knn_kernel(const float* __restrict__ xyz,
                                                  const float* __restrict__ centers,
                                                  float* __restrict__ grouped) {
  __shared__ float spts[1024 * 3];
  __shared__ u64 cand[8][192];
  __shared__ int ccnt[8];
  const int t = threadIdx.x;
  const int lane = t & 63;
  const int w = t >> 6;
  const int cg = blockIdx.x * 8 + w;   // global center id
  const int b = cg >> 9;               // / 512
  const float* xb = xyz + (size_t)b * NPTS * 3;
  const float cx = centers[cg * 3 + 0];
  const float cy = centers[cg * 3 + 1];
  const float cz = centers[cg * 3 + 2];
  if (lane == 0) ccnt[w] = 0;

  // phase 1: per-lane min (packed (d,idx))
  u64 lmin = ~0ull;
  for (int ch = 0; ch < 16; ++ch) {
    __syncthreads();
    const float* src = xb + ch * 1024 * 3;
#pragma unroll
    for (int q = 0; q < 6; ++q) spts[q * 512 + t] = src[q * 512 + t];
    __syncthreads();
#pragma unroll
    for (int j = 0; j < 16; ++j) {
      int p = lane + j * 64;
      float dx = __fsub_rn(cx, spts[p * 3 + 0]);
      float dy = __fsub_rn(cy, spts[p * 3 + 1]);
      float dz = __fsub_rn(cz, spts[p * 3 + 2]);
      float d = __fadd_rn(__fadd_rn(__fmul_rn(dx, dx), __fmul_rn(dy, dy)), __fmul_rn(dz, dz));
      u64 kk = ((u64)__float_as_uint(d) << 32) | (u64)(u32)(ch * 1024 + p);
      lmin = kk < lmin ? kk : lmin;
    }
  }
  // bitonic sort (ascending) of 64 lane-minima; tau = 32nd smallest
  u64 v = lmin;
  for (int k = 2; k <= 64; k <<= 1)
    for (int j = k >> 1; j > 0; j >>= 1) {
      u64 o = shflx64(v, j);
      bool up = ((lane & k) == 0);
      bool lowr = ((lane & j) == 0);
      u64 mn = v < o ? v : o;
      u64 mx = v < o ? o : v;
      v = (lowr == up) ? mn : mx;
    }
  u64 tau = shfl64(v, 31);
  float tf = __uint_as_float((u32)(tau >> 32));

  // phase 2: collect candidates d <= tf  (guaranteed >= 32 of them)
  for (int ch = 0; ch < 16; ++ch) {
    __syncthreads();
    const float* src = xb + ch * 1024 * 3;
#pragma unroll
    for (int q = 0; q < 6; ++q) spts[q * 512 + t] = src[q * 512 + t];
    __syncthreads();
#pragma unroll
    for (int j = 0; j < 16; ++j) {
      int p = lane + j * 64;
      float dx = __fsub_rn(cx, spts[p * 3 + 0]);
      float dy = __fsub_rn(cy, spts[p * 3 + 1]);
      float dz = __fsub_rn(cz, spts[p * 3 + 2]);
      float d = __fadd_rn(__fadd_rn(__fmul_rn(dx, dx), __fmul_rn(dy, dy)), __fmul_rn(dz, dz));
      if (d <= tf) {
        int pos = atomicAdd(&ccnt[w], 1);
        if (pos < 192) cand[w][pos] = ((u64)__float_as_uint(d) << 32) | (u64)(u32)(ch * 1024 + p);
      }
    }
  }
  __syncthreads();
  int cnt = ccnt[w];
  u32 myn = 0u;  // lane r (<32) keeps r-th nearest neighbor's index
  if (cnt <= 192) {
    u64 c0 = (lane < cnt) ? cand[w][lane] : ~0ull;
    u64 c1 = (64 + lane < cnt) ? cand[w][64 + lane] : ~0ull;
    u64 c2 = (128 + lane < cnt) ? cand[w][128 + lane] : ~0ull;
    csw(c0, c1); csw(c1, c2); csw(c0, c1);  // c0<=c1<=c2
    for (int r = 0; r < 32; ++r) {
      u64 wm = c0;
      for (int s = 32; s; s >>= 1) {
        u64 o = shflx64(wm, s);
        wm = o < wm ? o : wm;
      }
      if (c0 == wm) { c0 = c1; c1 = c2; c2 = ~0ull; }
      if (lane == r) myn = (u32)wm;
    }
  } else {
    // exact slow fallback (astronomically rare): ascending extraction
    u64 last = 0ull;
    for (int r = 0; r < 32; ++r) {
      u64 bb = ~0ull;
      for (int j = 0; j < 256; ++j) {
        int p = lane + j * 64;
        float dx = __fsub_rn(cx, xb[p * 3 + 0]);
        float dy = __fsub_rn(cy, xb[p * 3 + 1]);
        float dz = __fsub_rn(cz, xb[p * 3 + 2]);
        float d = __fadd_rn(__fadd_rn(__fmul_rn(dx, dx), __fmul_rn(dy, dy)), __fmul_rn(dz, dz));
        u64 kk = ((u64)__float_as_uint(d) << 32) | (u64)(u32)p;
        if (r == 0 || kk > last)
          if (kk < bb) bb = kk;
      }
      for (int s = 32; s; s >>= 1) {
        u64 o = shflx64(bb, s);
        bb = o < bb ? o : bb;
      }
      last = bb;
      if (lane == r) myn = (u32)bb;
    }
  }
  if (lane < 32) {
    const float nx = xb[(size_t)myn * 3 + 0];
    const float ny = xb[(size_t)myn * 3 + 1];
    const float nz = xb[(size_t)myn * 3 + 2];
    float* gp = grouped + ((size_t)cg * 32 + lane) * 3;
    gp[0] = __fsub_rn(nx, cx);
    gp[1] = __fsub_rn(ny, cy);
    gp[2] = __fsub_rn(nz, cz);
  }
}

// ---------------------------------------------------------------------------
// Weight prep: fold eval-BN into weights, bf16 + MFMA-fragment-swizzled
// layouts for W2/W3 so the MLP kernel stages LDS with a linear copy.
// ---------------------------------------------------------------------------
__global__ __launch_bounds__(256) void prep_kernel(
    const float* __restrict__ W1, const float* __restrict__ b1,
    const float* __restrict__ g1, const float* __restrict__ be1,
    const float* __restrict__ m1, const float* __restrict__ v1,
    const float* __restrict__ W2, const float* __restrict__ b2,
    const float* __restrict__ g2, const float* __restrict__ be2,
    const float* __restrict__ m2, const float* __restrict__ v2,
    const float* __restrict__ W3,
    float* __restrict__ w1eff, u16* __restrict__ w2L,
    float* __restrict__ t2, u16* __restrict__ w3L) {
  const int tid = blockIdx.x * 256 + threadIdx.x;  // 128 blocks -> 32768
  if (tid < 64) {
    float s = g1[tid] / sqrtf(v1[tid] + 1e-5f);
    w1eff[tid * 4 + 0] = W1[tid * 3 + 0] * s;
    w1eff[tid * 4 + 1] = W1[tid * 3 + 1] * s;
    w1eff[tid * 4 + 2] = W1[tid * 3 + 2] * s;
    w1eff[tid * 4 + 3] = (b1[tid] - m1[tid]) * s + be1[tid];
  }
  if (tid < 128) {
    float s = g2[tid] / sqrtf(v2[tid] + 1e-5f);
    t2[tid] = (b2[tid] - m2[tid]) * s + be2[tid];
  }
  if (tid < 8192) {  // W2eff (128 out x 64 in), bn-scaled, as B-fragments
    int i = tid & 63, o = tid >> 6;
    float s = g2[o] / sqrtf(v2[o] + 1e-5f);
    int kg = i >> 3, j = i & 7;
    w2L[((((kg * 128) + o) * 8) ^ ((kg & 7) * 8)) + j] = bf16rne(W2[o * 64 + i] * s);
  }
  if (tid < 32768) {  // W3 (256 out x 128 in) as B-fragments, split in col-halves
    int i = tid & 127, o = tid >> 7;
    int kg = i >> 3, j = i & 7;
    int h = o >> 7, colh = o & 127;
    w3L[h * 16384 + ((((kg * 128) + colh) * 8) ^ ((kg & 7) * 8)) + j] = bf16rne(W3[o * 128 + i]);
  }
}

// ---------------------------------------------------------------------------
// MLP: 4 centers (128 rows) per 256-thread block; wave = one center.
// L1 on VALU (K=3), L2/L3 as bf16 MFMA GEMMs; fused max-pool + pos epilogue.
// LDS (64KB): [0,16K)=W2 (later W3 half over [0,32K)); [16K,32K)=H1; [32K,64K)=H2.
// ---------------------------------------------------------------------------
__global__ __launch_bounds__(256) void mlp_kernel(
    const float* __restrict__ grouped, const u16* __restrict__ w2L,
    const u16* __restrict__ w3L, const float* __restrict__ w1eff,
    const float* __restrict__ t2, const float* __restrict__ b3,
    const float* __restrict__ Wp, const float* __restrict__ bp,
    const float* __restrict__ centers, float* __restrict__ tokens) {
  __shared__ char lds[65536];
  const int t = threadIdx.x;
  const int lane = t & 63;
  const int w = t >> 6;
  const int l15 = lane & 15;
  const int lg = lane >> 4;
  const int c0 = blockIdx.x * 4;
  {  // stage W2 -> [0,16K)
    const u32* s = (const u32*)w2L;
    u32* d = (u32*)lds;
#pragma unroll
    for (int q = 0; q < 16; ++q) d[q * 256 + t] = s[q * 256 + t];
  }
  {  // H1 = relu(X @ W1eff^T + b1eff), bf16, swizzled -> [16K,32K)
    const int row = t & 127;
    const int oh = (t >> 7) * 32;
    const int cg = c0 + (row >> 5);
    const float* gp = grouped + ((size_t)cg * 32 + (row & 31)) * 3;
    const float gx = gp[0], gy = gp[1], gz = gp[2];
    u16 hv[32];
#pragma unroll
    for (int o = 0; o < 32; ++o) {
      const float4 wvv = ((const float4*)w1eff)[oh + o];
      float h = fmaxf(0.f, gx * wvv.x + gy * wvv.y + gz * wvv.z + wvv.w);
      hv[o] = bf16rne(h);
    }
#pragma unroll
    for (int c4 = 0; c4 < 4; ++c4) {
      uint4 pk;
      pk.x = (u32)hv[c4 * 8 + 0] | ((u32)hv[c4 * 8 + 1] << 16);
      pk.y = (u32)hv[c4 * 8 + 2] | ((u32)hv[c4 * 8 + 3] << 16);
      pk.z = (u32)hv[c4 * 8 + 4] | ((u32)hv[c4 * 8 + 5] << 16);
      pk.w = (u32)hv[c4 * 8 + 6] | ((u32)hv[c4 * 8 + 7] << 16);
      int byte = row * 128 + oh * 2 + c4 * 16;
      *reinterpret_cast<uint4*>(lds + 16384 + (byte ^ ((row & 7) << 4))) = pk;
    }
  }
  __syncthreads();
  // GEMM2: H2(32x128) = H1(32x64) @ W2eff^T, per wave
  f32x4 acc2[2][8];
#pragma unroll
  for (int m = 0; m < 2; ++m)
#pragma unroll
    for (int n = 0; n < 8; ++n) acc2[m][n] = (f32x4){0.f, 0.f, 0.f, 0.f};
#pragma unroll
  for (int ks = 0; ks < 2; ++ks) {
    bf16x8 a[2];
#pragma unroll
    for (int m = 0; m < 2; ++m) {
      int row = w * 32 + m * 16 + l15;
      int byte = row * 128 + (ks * 32 + lg * 8) * 2;
      a[m] = *reinterpret_cast<const bf16x8*>(lds + 16384 + (byte ^ ((row & 7) << 4)));
    }
    const int kg = ks * 4 + lg;
#pragma unroll
    for (int n = 0; n < 8; ++n) {
      int idx = (((kg * 128) + (n * 16 + l15)) * 8) ^ ((kg & 7) * 8);
      bf16x8 bb = *reinterpret_cast<const bf16x8*>((const u16*)lds + idx);
      acc2[0][n] = MFMA16(a[0], bb, acc2[0][n]);
      acc2[1][n] = MFMA16(a[1], bb, acc2[1][n]);
    }
  }
#pragma unroll
  for (int n = 0; n < 8; ++n) {  // relu(acc + t2) -> H2 bf16 swizzled
    const int col = n * 16 + l15;
    const float t2v = t2[col];
#pragma unroll
    for (int m = 0; m < 2; ++m)
#pragma unroll
      for (int r = 0; r < 4; ++r) {
        float vv = fmaxf(0.f, acc2[m][n][r] + t2v);
        int row = w * 32 + m * 16 + lg * 4 + r;
        int byte = row * 256 + col * 2;
        *reinterpret_cast<u16*>(lds + 32768 + (byte ^ ((row & 7) << 4))) = bf16rne(vv);
      }
  }
  __syncthreads();
  const float ccx = centers[(c0 + w) * 3 + 0];
  const float ccy = centers[(c0 + w) * 3 + 1];
  const float ccz = centers[(c0 + w) * 3 + 2];
  float* tok = tokens + (size_t)(c0 + w) * 256;
  for (int h = 0; h < 2; ++h) {
    {  // stage W3 col-half (32KB) -> [0,32K); H2 at [32K,64K) untouched
      const u32* s = (const u32*)w3L + h * 8192;
      u32* d = (u32*)lds;
#pragma unroll
      for (int q = 0; q < 32; ++q) d[q * 256 + t] = s[q * 256 + t];
    }
    __syncthreads();
    f32x4 acc3[2][8];
#pragma unroll
    for (int m = 0; m < 2; ++m)
#pragma unroll
      for (int n = 0; n < 8; ++n) acc3[m][n] = (f32x4){0.f, 0.f, 0.f, 0.f};
#pragma unroll
    for (int ks = 0; ks < 4; ++ks) {
      bf16x8 a[2];
#pragma unroll
      for (int m = 0; m < 2; ++m) {
        int row = w * 32 + m * 16 + l15;
        int byte = row * 256 + (ks * 32 + lg * 8) * 2;
        a[m] = *reinterpret_cast<const bf16x8*>(lds + 32768 + (byte ^ ((row & 7) << 4)));
      }
      const int kg = ks * 4 + lg;
#pragma unroll
      for (int n = 0; n < 8; ++n) {
        int idx = (((kg * 128) + (n * 16 + l15)) * 8) ^ ((kg & 7) * 8);
        bf16x8 bb = *reinterpret_cast<const bf16x8*>((const u16*)lds + idx);
        acc3[0][n] = MFMA16(a[0], bb, acc3[0][n]);
        acc3[1][n] = MFMA16(a[1], bb, acc3[1][n]);
      }
    }
#pragma unroll
    for (int n = 0; n < 8; ++n) {  // max over 32 neighbors + b3 + pos
      float vmx = acc3[0][n][0];
#pragma unroll
      for (int m = 0; m < 2; ++m)
#pragma unroll
        for (int r = 0; r < 4; ++r) vmx = fmaxf(vmx, acc3[m][n][r]);
      vmx = fmaxf(vmx, __shfl_xor(vmx, 16, 64));
      vmx = fmaxf(vmx, __shfl_xor(vmx, 32, 64));
      const int col = h * 128 + n * 16 + l15;
      if (lane < 16) {
        float pos = Wp[col * 3 + 0] * ccx + Wp[col * 3 + 1] * ccy +
                    Wp[col * 3 + 2] * ccz + bp[col] + b3[col];
        tok[col] = vmx + pos;
      }
    }
    __syncthreads();
  }
}

// ---------------------------------------------------------------------------
extern "C" void kernel_launch(void* const* d_in, const int* in_sizes, int n_in,
                              void* d_out, int out_size, void* d_ws, size_t ws_size,
                              hipStream_t stream) {
  const float* xyz = (const float*)d_in[0];
  const float* W1 = (const float*)d_in[1];
  const float* b1 = (const float*)d_in[2];
  const float* g1 = (const float*)d_in[3];
  const float* be1 = (const float*)d_in[4];
  const float* m1 = (const float*)d_in[5];
  const float* v1 = (const float*)d_in[6];
  const float* W2 = (const float*)d_in[7];
  const float* b2 = (const float*)d_in[8];
  const float* g2 = (const float*)d_in[9];
  const float* be2 = (const float*)d_in[10];
  const float* m2 = (const float*)d_in[11];
  const float* v2 = (const float*)d_in[12];
  const float* W3 = (const float*)d_in[13];
  const float* b3 = (const float*)d_in[14];
  const float* Wp = (const float*)d_in[15];
  const float* bp = (const float*)d_in[16];

  char* ws = (char*)d_ws;
  float* grouped = (float*)ws;                      // 4096*32*3 f32 = 1572864 B
  float* w1eff = (float*)(ws + 1572864);            // 64*4 f32     = 1024 B
  u16* w2L = (u16*)(ws + 1573888);                  // 8192 u16     = 16384 B
  float* t2 = (float*)(ws + 1590272);               // 128 f32      = 512 B
  u16* w3L = (u16*)(ws + 1590784);                  // 32768 u16    = 65536 B

  float* centers = (float*)d_out;                   // (8,512,3)
  float* tokens = (float*)d_out + 8 * 512 * 3;      // (8,512,256)

  prep_kernel<<<dim3(128), dim3(256), 0, stream>>>(W1, b1, g1, be1, m1, v1,
                                                   W2, b2, g2, be2, m2, v2, W3,
                                                   w1eff, w2L, t2, w3L);
  fps_kernel<<<dim3(8), dim3(1024), 0, stream>>>(xyz, centers);
  knn_kernel<<<dim3(512), dim3(512), 0, stream>>>(xyz, centers, grouped);
  mlp_kernel<<<dim3(1024), dim3(256), 0, stream>>>(grouped, w2L, w3L, w1eff, t2,
                                                   b3, Wp, bp, centers, tokens);
}